// Round 3
// baseline (1698.456 us; speedup 1.0000x reference)
//
#include <hip/hip_runtime.h>

#define NBATCH 8
#define NA 1000
#define MD 64
#define GD 50
#define FD 128
#define TOTAL (NBATCH * NA)  // 8000 atoms

// ---------------- kernel A: init = features @ W_init ----------------
// one block per atom row; thread f computes one output feature.
__global__ __launch_bounds__(128) void ka_init(const float* __restrict__ feat,
                                               const float* __restrict__ Wi,
                                               float* __restrict__ initB) {
    __shared__ float fr[FD];
    const int row = blockIdx.x;
    const int f = threadIdx.x;
    fr[f] = feat[row * FD + f];
    __syncthreads();
    float s = 0.f;
#pragma unroll 8
    for (int k = 0; k < FD; ++k) s += fr[k] * Wi[k * FD + f];
    initB[row * FD + f] = s;
}

// ---------------- kernel B: everything else, one atom per block ----------------
__global__ __launch_bounds__(256) void kb_main(
    const float* __restrict__ rbf, const int* __restrict__ nl,
    const float* __restrict__ initB,
    const float* __restrict__ W1, const float* __restrict__ b1,
    const float* __restrict__ W2, const float* __restrict__ b2,
    const float* __restrict__ nbrw,
    const float* __restrict__ Wo1, const float* __restrict__ bo1,
    const float* __restrict__ Wo2, const float* __restrict__ bo2,
    float* __restrict__ outp, float* __restrict__ attnp) {
    __shared__ alignas(16) char smem[48128];
    float* rbfS  = (float*)(smem);          // [64][50]  12800 B
    float* h1S   = (float*)(smem + 12800);  // [64][128] 32768 B (reused as convS)
    int*   nlS   = (int*)(smem + 45568);    // [64]        256 B
    float* nbS   = (float*)(smem + 45824);  // [128]       512 B
    float* partS = (float*)(smem + 46336);  // [256]      1024 B (reused)
    float* attnS = (float*)(smem + 47360);  // [64]        256 B
    float* aggS  = (float*)(smem + 47616);  // [128]       512 B

    const int tid = threadIdx.x;
    const int atom = blockIdx.x;
    const int b = atom / NA;
    const int f = tid & 127;
    const int mh = tid >> 7;  // 0 or 1: which half of the 64 neighbors

    // ---- stage ----
    if (tid < MD) nlS[tid] = nl[atom * MD + tid];
    if (tid >= 128 && tid < 256) nbS[tid - 128] = nbrw[tid - 128];
    for (int i = tid; i < MD * GD; i += 256)
        rbfS[i] = rbf[(size_t)atom * (MD * GD) + i];
    __syncthreads();

    // ---- layer 1: h1 = tanh(rbf @ W1 + b1), [64][128] fp32 in LDS ----
    {
        const float bias = b1[f];
        for (int mi = 0; mi < 32; ++mi) {
            const int m = mh * 32 + mi;
            float s = bias;
#pragma unroll 10
            for (int g = 0; g < GD; ++g) s += rbfS[m * GD + g] * W1[g * FD + f];
            h1S[m * FD + f] = tanhf(s);
        }
    }
    __syncthreads();

    // ---- layer 2 + gather + conv: conv[m][f] = (h1 @ W2 + b2)[m][f] * init[nbr[m]][f] ----
    float convR[32];
    {
        const float bias = b2[f];
        for (int mi = 0; mi < 32; ++mi) {
            const int m = mh * 32 + mi;
            float s = bias;
#pragma unroll 8
            for (int k = 0; k < FD; ++k) s += h1S[m * FD + k] * W2[k * FD + f];
            const float nb = initB[(size_t)(b * NA + nlS[m]) * FD + f];
            convR[mi] = s * nb;
        }
    }
    __syncthreads();  // all h1S reads done before overwrite
    float* convS = h1S;  // reuse [64][128]
    for (int mi = 0; mi < 32; ++mi) convS[(mh * 32 + mi) * FD + f] = convR[mi];
    __syncthreads();

    // ---- logits: logit[m] = sum_f conv[m][f] * nbr_w[f] ----
    {
        const int m = tid >> 2, q = tid & 3;
        float s = 0.f;
#pragma unroll 8
        for (int j = 0; j < 32; ++j) {
            const int ff = q * 32 + j;
            s += convS[m * FD + ff] * nbS[ff];
        }
        partS[tid] = s;  // partS[m*4 + q]
    }
    __syncthreads();

    // ---- softmax over 64 neighbors (wave 0) + attn output ----
    if (tid < MD) {
        float x = partS[tid * 4] + partS[tid * 4 + 1] + partS[tid * 4 + 2] +
                  partS[tid * 4 + 3];
        float mx = x;
#pragma unroll
        for (int d = 1; d < 64; d <<= 1) mx = fmaxf(mx, __shfl_xor(mx, d, 64));
        float e = expf(x - mx);
        float ssum = e;
#pragma unroll
        for (int d = 1; d < 64; d <<= 1) ssum += __shfl_xor(ssum, d, 64);
        float a = e / ssum;
        attnS[tid] = a;
        attnp[(size_t)atom * MD + tid] = a;
    }
    __syncthreads();

    // ---- agg[f] = sum_m attn[m] * conv[m][f] ----
    {
        float s = 0.f;
        for (int mi = 0; mi < 32; ++mi) {
            const int m = mh * 32 + mi;
            s += attnS[m] * convS[m * FD + f];
        }
        partS[tid] = s;  // partS[mh*128 + f]
    }
    __syncthreads();
    if (tid < FD) aggS[tid] = partS[tid] + partS[FD + tid];
    __syncthreads();

    // ---- output dense: out = tanh(agg @ Wo1 + bo1) @ Wo2 + bo2 ----
    if (tid < FD) {
        float s = bo1[tid];
#pragma unroll 8
        for (int k = 0; k < FD; ++k) s += aggS[k] * Wo1[k * FD + tid];
        partS[tid] = tanhf(s);  // t1 in partS[0..128)
    }
    __syncthreads();
    if (tid < FD) {
        float s = bo2[tid];
#pragma unroll 8
        for (int k = 0; k < FD; ++k) s += partS[k] * Wo2[k * FD + tid];
        outp[(size_t)atom * FD + tid] = s;
    }
}

extern "C" void kernel_launch(void* const* d_in, const int* in_sizes, int n_in,
                              void* d_out, int out_size, void* d_ws,
                              size_t ws_size, hipStream_t stream) {
    const float* feat = (const float*)d_in[0];
    const float* rbf  = (const float*)d_in[1];
    const int*   nl   = (const int*)d_in[2];
    const float* Wi   = (const float*)d_in[3];
    const float* W1   = (const float*)d_in[4];
    const float* b1   = (const float*)d_in[5];
    const float* W2   = (const float*)d_in[6];
    const float* b2   = (const float*)d_in[7];
    const float* nbrw = (const float*)d_in[8];
    const float* Wo1  = (const float*)d_in[9];
    const float* bo1  = (const float*)d_in[10];
    const float* Wo2  = (const float*)d_in[11];
    const float* bo2  = (const float*)d_in[12];

    float* outp  = (float*)d_out;                // [8000][128]
    float* attnp = outp + (size_t)TOTAL * FD;    // [8000][64]

    float* initB = (float*)d_ws;                 // 4,096,000 B scratch

    hipLaunchKernelGGL(ka_init, dim3(TOTAL), dim3(128), 0, stream,
                       feat, Wi, initB);
    hipLaunchKernelGGL(kb_main, dim3(TOTAL), dim3(256), 0, stream,
                       rbf, nl, initB, W1, b1, W2, b2, nbrw,
                       Wo1, bo1, Wo2, bo2, outp, attnp);
}

// Round 4
// 361.221 us; speedup vs baseline: 4.7020x; 4.7020x over previous
//
#include <hip/hip_runtime.h>

typedef __attribute__((ext_vector_type(8))) short short8;
typedef __attribute__((ext_vector_type(4))) float f32x4;
typedef unsigned short u16;
typedef unsigned int u32;

#define NBATCH 8
#define NA 1000
#define MD 64
#define GD 50
#define FD 128
#define TOTAL (NBATCH * NA)  // 8000

__device__ __forceinline__ u16 f2bf(float f) {
    u32 x = __float_as_uint(f);
    return (u16)((x + 0x7fffu + ((x >> 16) & 1u)) >> 16);  // RNE
}
__device__ __forceinline__ float bf2f(u16 u) {
    return __uint_as_float(((u32)u) << 16);
}
__device__ __forceinline__ float tanh_fast(float x) {
    float e = __expf(2.0f * x);
    return 1.0f - 2.0f * __builtin_amdgcn_rcpf(e + 1.0f);
}
__device__ __forceinline__ f32x4 mfma16(short8 a, short8 b, f32x4 c) {
    return __builtin_amdgcn_mfma_f32_16x16x32_bf16(a, b, c, 0, 0, 0);
}

// ---------------- k0: fp32 weights -> bf16 transposed/padded panels ----------------
// W1T: [128 n][72 k], k<50 valid else 0.
// W2T/WiT/Wo1T/Wo2T: [2 p][128 n][72 kk], k=p*64+kk, kk<64 valid else 0.
__global__ void k0_prep(const float* __restrict__ W1, const float* __restrict__ W2,
                        const float* __restrict__ Wi, const float* __restrict__ Wo1,
                        const float* __restrict__ Wo2,
                        u16* __restrict__ W1T, u16* __restrict__ W2T,
                        u16* __restrict__ WiT, u16* __restrict__ Wo1T,
                        u16* __restrict__ Wo2T) {
    const int tid = threadIdx.x;
    for (int i = tid; i < 128 * 72; i += 256) {
        int n = i / 72, k = i - n * 72;
        int ks = (k < GD) ? k : 0;
        W1T[i] = (k < GD) ? f2bf(W1[ks * FD + n]) : (u16)0;
    }
    for (int i = tid; i < 2 * 128 * 72; i += 256) {
        int p = i / 9216;
        int rem = i - p * 9216;
        int n = rem / 72, kk = rem - n * 72;
        bool valid = kk < 64;
        int k = p * 64 + (valid ? kk : 0);  // clamped, in-bounds
        W2T[i]  = valid ? f2bf(W2[k * FD + n])  : (u16)0;
        WiT[i]  = valid ? f2bf(Wi[k * FD + n])  : (u16)0;
        Wo1T[i] = valid ? f2bf(Wo1[k * FD + n]) : (u16)0;
        Wo2T[i] = valid ? f2bf(Wo2[k * FD + n]) : (u16)0;
    }
}

// ---------------- k1: init = features @ W_init -> bf16 in ws ----------------
__global__ __launch_bounds__(256, 2) void k1_init(const float* __restrict__ feat,
                                                  const u16* __restrict__ WiT,
                                                  u16* __restrict__ initB) {
    __shared__ alignas(16) char smem[53248];
    u16* sA = (u16*)smem;              // [128][136] bf16
    u16* sW = (u16*)(smem + 34816);    // [128][72] panel
    const int tid = threadIdx.x, wid = tid >> 6, lane = tid & 63;
    const int quad = lane >> 4, col = lane & 15, rw = wid * 32;
    const int row0 = blockIdx.x * 128;

    for (int i = tid; i < 4096; i += 256) {
        int r = i >> 5, c = (i & 31) * 4;
        int gr = row0 + r;
        float4 v = {0.f, 0.f, 0.f, 0.f};
        if (gr < TOTAL) v = *(const float4*)&feat[(size_t)gr * FD + c];
        u32 lo = (u32)f2bf(v.x) | ((u32)f2bf(v.y) << 16);
        u32 hi = (u32)f2bf(v.z) | ((u32)f2bf(v.w) << 16);
        u32* p = (u32*)&sA[r * 136 + c];
        p[0] = lo;
        p[1] = hi;
    }
    for (int i = tid; i < 1152; i += 256) ((int4*)sW)[i] = ((const int4*)WiT)[i];
    __syncthreads();

    f32x4 acc[2][8];
    const f32x4 zf = {0.f, 0.f, 0.f, 0.f};
#pragma unroll
    for (int mt = 0; mt < 2; ++mt)
#pragma unroll
        for (int nt = 0; nt < 8; ++nt) acc[mt][nt] = zf;

    for (int half = 0; half < 2; ++half) {
        if (half) {
            __syncthreads();
            for (int i = tid; i < 1152; i += 256)
                ((int4*)sW)[i] = ((const int4*)(WiT + 9216))[i];
            __syncthreads();
        }
#pragma unroll
        for (int ks = 0; ks < 2; ++ks) {
            const int ka = half * 64 + ks * 32 + quad * 8;
            const int kb = ks * 32 + quad * 8;
            short8 a0 = *(const short8*)&sA[(rw + col) * 136 + ka];
            short8 a1 = *(const short8*)&sA[(rw + 16 + col) * 136 + ka];
#pragma unroll
            for (int nt = 0; nt < 8; ++nt) {
                short8 bfr = *(const short8*)&sW[(nt * 16 + col) * 72 + kb];
                acc[0][nt] = mfma16(a0, bfr, acc[0][nt]);
                acc[1][nt] = mfma16(a1, bfr, acc[1][nt]);
            }
        }
    }
#pragma unroll
    for (int mt = 0; mt < 2; ++mt)
#pragma unroll
        for (int nt = 0; nt < 8; ++nt)
#pragma unroll
            for (int r = 0; r < 4; ++r) {
                int row = rw + mt * 16 + quad * 4 + r;
                int gr = row0 + row;
                if (gr < TOTAL)
                    initB[(size_t)gr * FD + nt * 16 + col] = f2bf(acc[mt][nt][r]);
            }
}

// ---------------- k2: fused CFConv + attention, 2 atoms / block ----------------
__global__ __launch_bounds__(256, 2) void k2_main(
    const float* __restrict__ rbf, const int* __restrict__ nl,
    const u16* __restrict__ initB,
    const u16* __restrict__ W1T, const u16* __restrict__ W2T,
    const float* __restrict__ b1, const float* __restrict__ b2,
    const float* __restrict__ nbrw,
    float* __restrict__ aggOut, float* __restrict__ attnO) {
    __shared__ alignas(16) char smem[58880];
    u16* sA  = (u16*)smem;             // rbfp [128][72] -> H [128][136]
    u16* sW1 = (u16*)(smem + 18432);   // [128][72] (overwritten by H later)
    u16* sW2 = (u16*)(smem + 36864);   // [128][72] K-panel of W2
    float* logitS = (float*)(smem + 55296);  // [128]
    float* attnS  = (float*)(smem + 55808);  // [128]
    float* aggS   = (float*)(smem + 56320);  // [4][128]
    int*   nlS    = (int*)(smem + 58368);    // [128]

    const int tid = threadIdx.x, wid = tid >> 6, lane = tid & 63;
    const int quad = lane >> 4, col = lane & 15, rw = wid * 32;
    const int blk = blockIdx.x;
    const int b = blk / 500;
    const int n0 = (blk - b * 500) * 2;
    const int atom0 = b * NA + n0;
    const size_t rbf_base = (size_t)atom0 * (MD * GD);

    if (tid < 128) nlS[tid] = nl[atom0 * MD + tid];
    // zero pad cols [50,72)
    for (int i = tid; i < 128 * 22; i += 256) {
        int r = i / 22;
        sA[r * 72 + 50 + (i - r * 22)] = 0;
    }
    // rbf fp32 -> bf16 (coalesced dword loads)
    for (int i = tid; i < 6400; i += 256) {
        int r = i / 50, g = i - r * 50;
        sA[r * 72 + g] = f2bf(rbf[rbf_base + i]);
    }
    for (int i = tid; i < 1152; i += 256) ((int4*)sW1)[i] = ((const int4*)W1T)[i];
    __syncthreads();

    // ---- layer 1: rbf @ W1 ----
    f32x4 acc[2][8];
    const f32x4 zf = {0.f, 0.f, 0.f, 0.f};
#pragma unroll
    for (int mt = 0; mt < 2; ++mt)
#pragma unroll
        for (int nt = 0; nt < 8; ++nt) acc[mt][nt] = zf;
#pragma unroll
    for (int ks = 0; ks < 2; ++ks) {
        const int ka = ks * 32 + quad * 8;
        short8 a0 = *(const short8*)&sA[(rw + col) * 72 + ka];
        short8 a1 = *(const short8*)&sA[(rw + 16 + col) * 72 + ka];
#pragma unroll
        for (int nt = 0; nt < 8; ++nt) {
            short8 bfr = *(const short8*)&sW1[(nt * 16 + col) * 72 + ka];
            acc[0][nt] = mfma16(a0, bfr, acc[0][nt]);
            acc[1][nt] = mfma16(a1, bfr, acc[1][nt]);
        }
    }
    __syncthreads();  // rbf/W1 reads complete before H overwrite

    // H = tanh(.+b1) -> sA [128][136] bf16; stage W2 panel 0
    float bias[8];
#pragma unroll
    for (int nt = 0; nt < 8; ++nt) bias[nt] = b1[nt * 16 + col];
#pragma unroll
    for (int mt = 0; mt < 2; ++mt)
#pragma unroll
        for (int nt = 0; nt < 8; ++nt)
#pragma unroll
            for (int r = 0; r < 4; ++r) {
                int row = rw + mt * 16 + quad * 4 + r;
                sA[row * 136 + nt * 16 + col] =
                    f2bf(tanh_fast(acc[mt][nt][r] + bias[nt]));
            }
    for (int i = tid; i < 1152; i += 256) ((int4*)sW2)[i] = ((const int4*)W2T)[i];
    __syncthreads();

    // ---- layer 2: H @ W2 ----
    f32x4 acc2[2][8];
#pragma unroll
    for (int mt = 0; mt < 2; ++mt)
#pragma unroll
        for (int nt = 0; nt < 8; ++nt) acc2[mt][nt] = zf;
    for (int half = 0; half < 2; ++half) {
        if (half) {
            __syncthreads();
            for (int i = tid; i < 1152; i += 256)
                ((int4*)sW2)[i] = ((const int4*)(W2T + 9216))[i];
            __syncthreads();
        }
#pragma unroll
        for (int ks = 0; ks < 2; ++ks) {
            const int ka = half * 64 + ks * 32 + quad * 8;
            const int kb = ks * 32 + quad * 8;
            short8 a0 = *(const short8*)&sA[(rw + col) * 136 + ka];
            short8 a1 = *(const short8*)&sA[(rw + 16 + col) * 136 + ka];
#pragma unroll
            for (int nt = 0; nt < 8; ++nt) {
                short8 bfr = *(const short8*)&sW2[(nt * 16 + col) * 72 + kb];
                acc2[0][nt] = mfma16(a0, bfr, acc2[0][nt]);
                acc2[1][nt] = mfma16(a1, bfr, acc2[1][nt]);
            }
        }
    }

    // ---- epilogue: conv, logits, softmax, agg ----
    float wv[8];
#pragma unroll
    for (int nt = 0; nt < 8; ++nt) {
        bias[nt] = b2[nt * 16 + col];
        wv[nt] = nbrw[nt * 16 + col];
    }
    int rowoff[2][4];
#pragma unroll
    for (int mt = 0; mt < 2; ++mt)
#pragma unroll
        for (int r = 0; r < 4; ++r) {
            int rr = rw + mt * 16 + quad * 4 + r;
            rowoff[mt][r] = (b * NA + nlS[rr]) * FD;
        }
    float part[2][4] = {{0.f, 0.f, 0.f, 0.f}, {0.f, 0.f, 0.f, 0.f}};
#pragma unroll
    for (int mt = 0; mt < 2; ++mt)
#pragma unroll
        for (int nt = 0; nt < 8; ++nt)
#pragma unroll
            for (int r = 0; r < 4; ++r) {
                float nb = bf2f(initB[rowoff[mt][r] + nt * 16 + col]);
                float cv = nb * (acc2[mt][nt][r] + bias[nt]);
                acc2[mt][nt][r] = cv;  // conv stays in regs (fp32)
                part[mt][r] += cv * wv[nt];
            }
#pragma unroll
    for (int d = 1; d < 16; d <<= 1)
#pragma unroll
        for (int mt = 0; mt < 2; ++mt)
#pragma unroll
            for (int r = 0; r < 4; ++r)
                part[mt][r] += __shfl_xor(part[mt][r], d, 64);
    if (col == 0) {
#pragma unroll
        for (int mt = 0; mt < 2; ++mt)
#pragma unroll
            for (int r = 0; r < 4; ++r)
                logitS[rw + mt * 16 + quad * 4 + r] = part[mt][r];
    }
    __syncthreads();

    if (wid < 2) {  // wave w -> atom0+w
        float x = logitS[wid * 64 + lane];
        float m = x;
#pragma unroll
        for (int d = 1; d < 64; d <<= 1) m = fmaxf(m, __shfl_xor(m, d, 64));
        float e = __expf(x - m);
        float s = e;
#pragma unroll
        for (int d = 1; d < 64; d <<= 1) s += __shfl_xor(s, d, 64);
        float a = e / s;
        attnS[wid * 64 + lane] = a;
        attnO[(size_t)(atom0 + wid) * MD + lane] = a;
    }
    __syncthreads();

    float aggp[8] = {0.f, 0.f, 0.f, 0.f, 0.f, 0.f, 0.f, 0.f};
#pragma unroll
    for (int mt = 0; mt < 2; ++mt)
#pragma unroll
        for (int r = 0; r < 4; ++r) {
            float a = attnS[rw + mt * 16 + quad * 4 + r];
#pragma unroll
            for (int nt = 0; nt < 8; ++nt) aggp[nt] += a * acc2[mt][nt][r];
        }
#pragma unroll
    for (int d = 16; d < 64; d <<= 1)
#pragma unroll
        for (int nt = 0; nt < 8; ++nt) aggp[nt] += __shfl_xor(aggp[nt], d, 64);
    if (quad == 0) {
#pragma unroll
        for (int nt = 0; nt < 8; ++nt) aggS[wid * 128 + nt * 16 + col] = aggp[nt];
    }
    __syncthreads();
    {
        int a = tid >> 7;       // which atom
        int c = tid & 127;      // feature
        float v = aggS[(2 * a) * 128 + c] + aggS[(2 * a + 1) * 128 + c];
        aggOut[(size_t)(atom0 + a) * FD + c] = v;  // agg scratch in d_out rows
    }
}

// ---------------- k3: out = tanh(agg@Wo1+bo1)@Wo2+bo2, IN PLACE on d_out rows ----------------
__global__ __launch_bounds__(256, 2) void k3_out(
    float* __restrict__ outp, const u16* __restrict__ Wo1T,
    const u16* __restrict__ Wo2T, const float* __restrict__ bo1,
    const float* __restrict__ bo2) {
    __shared__ alignas(16) char smem[53248];
    u16* sA = (u16*)smem;            // [128][136]: agg rows, then t1
    u16* sW = (u16*)(smem + 34816);  // [128][72] panel
    const int tid = threadIdx.x, wid = tid >> 6, lane = tid & 63;
    const int quad = lane >> 4, col = lane & 15, rw = wid * 32;
    const int row0 = blockIdx.x * 128;

    // stage agg (fp32, from d_out) -> bf16 LDS; ALL reads before first barrier
    for (int i = tid; i < 4096; i += 256) {
        int r = i >> 5, c = (i & 31) * 4;
        int gr = row0 + r;
        float4 v = {0.f, 0.f, 0.f, 0.f};
        if (gr < TOTAL) v = *(const float4*)&outp[(size_t)gr * FD + c];
        u32 lo = (u32)f2bf(v.x) | ((u32)f2bf(v.y) << 16);
        u32 hi = (u32)f2bf(v.z) | ((u32)f2bf(v.w) << 16);
        u32* p = (u32*)&sA[r * 136 + c];
        p[0] = lo;
        p[1] = hi;
    }
    for (int i = tid; i < 1152; i += 256) ((int4*)sW)[i] = ((const int4*)Wo1T)[i];
    __syncthreads();

    f32x4 acc[2][8];
    const f32x4 zf = {0.f, 0.f, 0.f, 0.f};
#pragma unroll
    for (int mt = 0; mt < 2; ++mt)
#pragma unroll
        for (int nt = 0; nt < 8; ++nt) acc[mt][nt] = zf;
    for (int half = 0; half < 2; ++half) {
        if (half) {
            __syncthreads();
            for (int i = tid; i < 1152; i += 256)
                ((int4*)sW)[i] = ((const int4*)(Wo1T + 9216))[i];
            __syncthreads();
        }
#pragma unroll
        for (int ks = 0; ks < 2; ++ks) {
            const int ka = half * 64 + ks * 32 + quad * 8;
            const int kb = ks * 32 + quad * 8;
            short8 a0 = *(const short8*)&sA[(rw + col) * 136 + ka];
            short8 a1 = *(const short8*)&sA[(rw + 16 + col) * 136 + ka];
#pragma unroll
            for (int nt = 0; nt < 8; ++nt) {
                short8 bfr = *(const short8*)&sW[(nt * 16 + col) * 72 + kb];
                acc[0][nt] = mfma16(a0, bfr, acc[0][nt]);
                acc[1][nt] = mfma16(a1, bfr, acc[1][nt]);
            }
        }
    }
    __syncthreads();  // layer-1 A reads done before t1 overwrite

    float bias[8];
#pragma unroll
    for (int nt = 0; nt < 8; ++nt) bias[nt] = bo1[nt * 16 + col];
#pragma unroll
    for (int mt = 0; mt < 2; ++mt)
#pragma unroll
        for (int nt = 0; nt < 8; ++nt)
#pragma unroll
            for (int r = 0; r < 4; ++r) {
                int row = rw + mt * 16 + quad * 4 + r;
                sA[row * 136 + nt * 16 + col] =
                    f2bf(tanh_fast(acc[mt][nt][r] + bias[nt]));
            }
    for (int i = tid; i < 1152; i += 256) ((int4*)sW)[i] = ((const int4*)Wo2T)[i];
    __syncthreads();

    f32x4 acc2[2][8];
#pragma unroll
    for (int mt = 0; mt < 2; ++mt)
#pragma unroll
        for (int nt = 0; nt < 8; ++nt) acc2[mt][nt] = zf;
    for (int half = 0; half < 2; ++half) {
        if (half) {
            __syncthreads();
            for (int i = tid; i < 1152; i += 256)
                ((int4*)sW)[i] = ((const int4*)(Wo2T + 9216))[i];
            __syncthreads();
        }
#pragma unroll
        for (int ks = 0; ks < 2; ++ks) {
            const int ka = half * 64 + ks * 32 + quad * 8;
            const int kb = ks * 32 + quad * 8;
            short8 a0 = *(const short8*)&sA[(rw + col) * 136 + ka];
            short8 a1 = *(const short8*)&sA[(rw + 16 + col) * 136 + ka];
#pragma unroll
            for (int nt = 0; nt < 8; ++nt) {
                short8 bfr = *(const short8*)&sW[(nt * 16 + col) * 72 + kb];
                acc2[0][nt] = mfma16(a0, bfr, acc2[0][nt]);
                acc2[1][nt] = mfma16(a1, bfr, acc2[1][nt]);
            }
        }
    }
#pragma unroll
    for (int nt = 0; nt < 8; ++nt) bias[nt] = bo2[nt * 16 + col];
#pragma unroll
    for (int mt = 0; mt < 2; ++mt)
#pragma unroll
        for (int nt = 0; nt < 8; ++nt)
#pragma unroll
            for (int r = 0; r < 4; ++r) {
                int row = rw + mt * 16 + quad * 4 + r;
                int gr = row0 + row;
                if (gr < TOTAL)
                    outp[(size_t)gr * FD + nt * 16 + col] =
                        acc2[mt][nt][r] + bias[nt];
            }
}

extern "C" void kernel_launch(void* const* d_in, const int* in_sizes, int n_in,
                              void* d_out, int out_size, void* d_ws,
                              size_t ws_size, hipStream_t stream) {
    const float* feat = (const float*)d_in[0];
    const float* rbf  = (const float*)d_in[1];
    const int*   nl   = (const int*)d_in[2];
    const float* Wi   = (const float*)d_in[3];
    const float* W1   = (const float*)d_in[4];
    const float* b1   = (const float*)d_in[5];
    const float* W2   = (const float*)d_in[6];
    const float* b2   = (const float*)d_in[7];
    const float* nbrw = (const float*)d_in[8];
    const float* Wo1  = (const float*)d_in[9];
    const float* bo1  = (const float*)d_in[10];
    const float* Wo2  = (const float*)d_in[11];
    const float* bo2  = (const float*)d_in[12];

    float* outp  = (float*)d_out;               // [8000][128] (agg scratch, then final)
    float* attnp = outp + (size_t)TOTAL * FD;   // [8000][64]

    char* ws = (char*)d_ws;                     // total use: 2,213,888 B
    u16* initB = (u16*)ws;                      // 2,048,000 B
    u16* W1T   = (u16*)(ws + 2048000);          // 18,432 B
    u16* W2T   = (u16*)(ws + 2048000 + 18432);  // 36,864 B
    u16* WiT   = (u16*)(ws + 2048000 + 18432 + 36864);
    u16* Wo1T  = (u16*)(ws + 2048000 + 18432 + 2 * 36864);
    u16* Wo2T  = (u16*)(ws + 2048000 + 18432 + 3 * 36864);

    hipLaunchKernelGGL(k0_prep, dim3(1), dim3(256), 0, stream,
                       W1, W2, Wi, Wo1, Wo2, W1T, W2T, WiT, Wo1T, Wo2T);
    hipLaunchKernelGGL(k1_init, dim3(63), dim3(256), 0, stream, feat, WiT, initB);
    hipLaunchKernelGGL(k2_main, dim3(4000), dim3(256), 0, stream,
                       rbf, nl, initB, W1T, W2T, b1, b2, nbrw, outp, attnp);
    hipLaunchKernelGGL(k3_out, dim3(63), dim3(256), 0, stream,
                       outp, Wo1T, Wo2T, bo1, bo2);
}

// Round 5
// 297.128 us; speedup vs baseline: 5.7163x; 1.2157x over previous
//
#include <hip/hip_runtime.h>
#include <hip/hip_bf16.h>

typedef __attribute__((ext_vector_type(8))) short short8;
typedef __attribute__((ext_vector_type(4))) float f32x4;
typedef unsigned short u16;
typedef unsigned int u32;

#define NBATCH 8
#define NA 1000
#define MD 64
#define GD 50
#define FD 128
#define TOTAL (NBATCH * NA)  // 8000

__device__ __forceinline__ u16 f2bf(float f) {
    u32 x = __float_as_uint(f);
    return (u16)((x + 0x7fffu + ((x >> 16) & 1u)) >> 16);  // RNE
}
__device__ __forceinline__ float bf2f(u16 u) {
    return __uint_as_float(((u32)u) << 16);
}
__device__ __forceinline__ u32 pkbf(float x, float y) {
    // packed fp32->bf16 RNE (v_cvt_pk_bf16_f32 on gfx950)
    __hip_bfloat162 h = __float22bfloat162_rn(float2{x, y});
    return *reinterpret_cast<u32*>(&h);
}
__device__ __forceinline__ float tanh_fast(float x) {
    float e = __expf(2.0f * x);
    return 1.0f - 2.0f * __builtin_amdgcn_rcpf(e + 1.0f);
}
__device__ __forceinline__ f32x4 mfma16(short8 a, short8 b, f32x4 c) {
    return __builtin_amdgcn_mfma_f32_16x16x32_bf16(a, b, c, 0, 0, 0);
}

// ---------------- k0: fp32 weights -> bf16 transposed/padded panels (40 blocks) ----------------
// W1T: [128 n][72 k], k<50 valid else 0.
// W2T/WiT/Wo1T/Wo2T: [2 p][128 n][72 kk], k=p*64+kk, kk<64 valid else 0.
__global__ void k0_prep(const float* __restrict__ W1, const float* __restrict__ W2,
                        const float* __restrict__ Wi, const float* __restrict__ Wo1,
                        const float* __restrict__ Wo2,
                        u16* __restrict__ W1T, u16* __restrict__ W2T,
                        u16* __restrict__ WiT, u16* __restrict__ Wo1T,
                        u16* __restrict__ Wo2T) {
    const int g0 = blockIdx.x * 256 + threadIdx.x;
    const int gstep = gridDim.x * 256;
    for (int i = g0; i < 128 * 72; i += gstep) {
        int n = i / 72, k = i - n * 72;
        int ks = (k < GD) ? k : 0;
        W1T[i] = (k < GD) ? f2bf(W1[ks * FD + n]) : (u16)0;
    }
    for (int i = g0; i < 2 * 128 * 72; i += gstep) {
        int p = i / 9216;
        int rem = i - p * 9216;
        int n = rem / 72, kk = rem - n * 72;
        bool valid = kk < 64;
        int k = p * 64 + (valid ? kk : 0);  // clamped, in-bounds
        W2T[i]  = valid ? f2bf(W2[k * FD + n])  : (u16)0;
        WiT[i]  = valid ? f2bf(Wi[k * FD + n])  : (u16)0;
        Wo1T[i] = valid ? f2bf(Wo1[k * FD + n]) : (u16)0;
        Wo2T[i] = valid ? f2bf(Wo2[k * FD + n]) : (u16)0;
    }
}

// ---------------- k1: init = features @ W_init -> bf16 in ws ----------------
__global__ __launch_bounds__(256, 3) void k1_init(const float* __restrict__ feat,
                                                  const u16* __restrict__ WiT,
                                                  u16* __restrict__ initB) {
    __shared__ alignas(16) char smem[53248];
    u16* sA = (u16*)smem;              // [128][136] bf16
    u16* sW = (u16*)(smem + 34816);    // [128][72] panel
    const int tid = threadIdx.x, wid = tid >> 6, lane = tid & 63;
    const int quad = lane >> 4, col = lane & 15, rw = wid * 32;
    const int row0 = blockIdx.x * 128;

    for (int i = tid; i < 4096; i += 256) {
        int r = i >> 5, c = (i & 31) * 4;
        int gr = row0 + r;
        float4 v = {0.f, 0.f, 0.f, 0.f};
        if (gr < TOTAL) v = *(const float4*)&feat[(size_t)gr * FD + c];
        u32* p = (u32*)&sA[r * 136 + c];
        p[0] = pkbf(v.x, v.y);
        p[1] = pkbf(v.z, v.w);
    }
    for (int i = tid; i < 1152; i += 256) ((int4*)sW)[i] = ((const int4*)WiT)[i];
    __syncthreads();

    f32x4 acc[2][8];
    const f32x4 zf = {0.f, 0.f, 0.f, 0.f};
#pragma unroll
    for (int mt = 0; mt < 2; ++mt)
#pragma unroll
        for (int nt = 0; nt < 8; ++nt) acc[mt][nt] = zf;

    for (int half = 0; half < 2; ++half) {
        if (half) {
            __syncthreads();
            for (int i = tid; i < 1152; i += 256)
                ((int4*)sW)[i] = ((const int4*)(WiT + 9216))[i];
            __syncthreads();
        }
#pragma unroll
        for (int ks = 0; ks < 2; ++ks) {
            const int ka = half * 64 + ks * 32 + quad * 8;
            const int kb = ks * 32 + quad * 8;
            short8 a0 = *(const short8*)&sA[(rw + col) * 136 + ka];
            short8 a1 = *(const short8*)&sA[(rw + 16 + col) * 136 + ka];
#pragma unroll
            for (int nt = 0; nt < 8; ++nt) {
                short8 bfr = *(const short8*)&sW[(nt * 16 + col) * 72 + kb];
                acc[0][nt] = mfma16(a0, bfr, acc[0][nt]);
                acc[1][nt] = mfma16(a1, bfr, acc[1][nt]);
            }
        }
    }
#pragma unroll
    for (int mt = 0; mt < 2; ++mt)
#pragma unroll
        for (int nt = 0; nt < 8; ++nt)
#pragma unroll
            for (int r = 0; r < 4; ++r) {
                int row = rw + mt * 16 + quad * 4 + r;
                int gr = row0 + row;
                if (gr < TOTAL)
                    initB[(size_t)gr * FD + nt * 16 + col] = f2bf(acc[mt][nt][r]);
            }
}

// ---------------- k2: fused CFConv + attention, 2 atoms / block ----------------
// LDS 53,760 B -> 3 blocks/CU.
__global__ __launch_bounds__(256, 3) void k2_main(
    const float* __restrict__ rbf, const int* __restrict__ nl,
    const u16* __restrict__ initB,
    const u16* __restrict__ W1T, const u16* __restrict__ W2T,
    const float* __restrict__ b1, const float* __restrict__ b2,
    const float* __restrict__ nbrw,
    float* __restrict__ aggOut, float* __restrict__ attnO) {
    __shared__ alignas(16) char smem[53760];
    u16* sA = (u16*)smem;              // rbf [128][72] -> H [128][136]
    u16* sB = (u16*)(smem + 34816);    // W1 -> W2 panel0 -> W2 panel1, [128][72]
    int* nlS = (int*)(smem + 53248);   // [128]
    // epilogue aux aliases sA (H dead by then):
    float* logitS = (float*)smem;            // [128]   bytes 0..511
    float* attnS  = (float*)(smem + 512);    // [128]   bytes 512..1023
    float* aggS   = (float*)(smem + 1024);   // [4][128] bytes 1024..3071

    const int tid = threadIdx.x, wid = tid >> 6, lane = tid & 63;
    const int quad = lane >> 4, col = lane & 15, rw = wid * 32;
    const int blk = blockIdx.x;
    const int b = blk / 500;
    const int n0 = (blk - b * 500) * 2;
    const int atom0 = b * NA + n0;
    const size_t rbf_base = (size_t)atom0 * (MD * GD);

    if (tid < 128) nlS[tid] = nl[atom0 * MD + tid];
    // zero pad cols [50,64) of rbf tile (K padded to 64)
    for (int i = tid; i < 128 * 14; i += 256) {
        int r = i / 14;
        sA[r * 72 + 50 + (i - r * 14)] = 0;
    }
    // rbf fp32 -> bf16 packed pairs (50 even: pairs never straddle rows)
    for (int i = tid; i < 3200; i += 256) {
        int e = 2 * i;
        int r = e / 50, g = e - r * 50;
        float2 v = *(const float2*)&rbf[rbf_base + e];
        *(u32*)&sA[r * 72 + g] = pkbf(v.x, v.y);
    }
    for (int i = tid; i < 1152; i += 256) ((int4*)sB)[i] = ((const int4*)W1T)[i];
    __syncthreads();

    // ---- layer 1: rbf @ W1 ----
    f32x4 acc[2][8];
    const f32x4 zf = {0.f, 0.f, 0.f, 0.f};
#pragma unroll
    for (int mt = 0; mt < 2; ++mt)
#pragma unroll
        for (int nt = 0; nt < 8; ++nt) acc[mt][nt] = zf;
#pragma unroll
    for (int ks = 0; ks < 2; ++ks) {
        const int ka = ks * 32 + quad * 8;
        short8 a0 = *(const short8*)&sA[(rw + col) * 72 + ka];
        short8 a1 = *(const short8*)&sA[(rw + 16 + col) * 72 + ka];
#pragma unroll
        for (int nt = 0; nt < 8; ++nt) {
            short8 bfr = *(const short8*)&sB[(nt * 16 + col) * 72 + ka];
            acc[0][nt] = mfma16(a0, bfr, acc[0][nt]);
            acc[1][nt] = mfma16(a1, bfr, acc[1][nt]);
        }
    }
    __syncthreads();  // rbf/W1 reads complete before overwrite

    // H = tanh(.+b1) -> sA [128][136]; stage W2 panel 0 into sB
    float bias[8];
#pragma unroll
    for (int nt = 0; nt < 8; ++nt) bias[nt] = b1[nt * 16 + col];
#pragma unroll
    for (int mt = 0; mt < 2; ++mt)
#pragma unroll
        for (int nt = 0; nt < 8; ++nt)
#pragma unroll
            for (int r = 0; r < 4; ++r) {
                int row = rw + mt * 16 + quad * 4 + r;
                sA[row * 136 + nt * 16 + col] =
                    f2bf(tanh_fast(acc[mt][nt][r] + bias[nt]));
            }
    for (int i = tid; i < 1152; i += 256) ((int4*)sB)[i] = ((const int4*)W2T)[i];
    __syncthreads();

    // ---- layer 2: H @ W2, two 64-K panels ----
    f32x4 acc2[2][8];
#pragma unroll
    for (int mt = 0; mt < 2; ++mt)
#pragma unroll
        for (int nt = 0; nt < 8; ++nt) acc2[mt][nt] = zf;
    for (int half = 0; half < 2; ++half) {
        if (half) {
            __syncthreads();
            for (int i = tid; i < 1152; i += 256)
                ((int4*)sB)[i] = ((const int4*)(W2T + 9216))[i];
            __syncthreads();
        }
#pragma unroll
        for (int ks = 0; ks < 2; ++ks) {
            const int ka = half * 64 + ks * 32 + quad * 8;
            const int kb = ks * 32 + quad * 8;
            short8 a0 = *(const short8*)&sA[(rw + col) * 136 + ka];
            short8 a1 = *(const short8*)&sA[(rw + 16 + col) * 136 + ka];
#pragma unroll
            for (int nt = 0; nt < 8; ++nt) {
                short8 bfr = *(const short8*)&sB[(nt * 16 + col) * 72 + kb];
                acc2[0][nt] = mfma16(a0, bfr, acc2[0][nt]);
                acc2[1][nt] = mfma16(a1, bfr, acc2[1][nt]);
            }
        }
    }

    // ---- epilogue: conv, logits, softmax, agg ----
    float wv[8];
#pragma unroll
    for (int nt = 0; nt < 8; ++nt) {
        bias[nt] = b2[nt * 16 + col];
        wv[nt] = nbrw[nt * 16 + col];
    }
    int rowoff[2][4];
#pragma unroll
    for (int mt = 0; mt < 2; ++mt)
#pragma unroll
        for (int r = 0; r < 4; ++r) {
            int rr = rw + mt * 16 + quad * 4 + r;
            rowoff[mt][r] = (b * NA + nlS[rr]) * FD;
        }
    float part[2][4] = {{0.f, 0.f, 0.f, 0.f}, {0.f, 0.f, 0.f, 0.f}};
#pragma unroll
    for (int mt = 0; mt < 2; ++mt)
#pragma unroll
        for (int nt = 0; nt < 8; ++nt)
#pragma unroll
            for (int r = 0; r < 4; ++r) {
                float nb = bf2f(initB[rowoff[mt][r] + nt * 16 + col]);
                float cv = nb * (acc2[mt][nt][r] + bias[nt]);
                acc2[mt][nt][r] = cv;  // conv stays in regs (fp32)
                part[mt][r] += cv * wv[nt];
            }
#pragma unroll
    for (int d = 1; d < 16; d <<= 1)
#pragma unroll
        for (int mt = 0; mt < 2; ++mt)
#pragma unroll
            for (int r = 0; r < 4; ++r)
                part[mt][r] += __shfl_xor(part[mt][r], d, 64);
    __syncthreads();  // all layer-2 LDS reads done before aux aliases sA
    if (col == 0) {
#pragma unroll
        for (int mt = 0; mt < 2; ++mt)
#pragma unroll
            for (int r = 0; r < 4; ++r)
                logitS[rw + mt * 16 + quad * 4 + r] = part[mt][r];
    }
    __syncthreads();

    if (wid < 2) {  // wave w -> atom0+w
        float x = logitS[wid * 64 + lane];
        float m = x;
#pragma unroll
        for (int d = 1; d < 64; d <<= 1) m = fmaxf(m, __shfl_xor(m, d, 64));
        float e = __expf(x - m);
        float s = e;
#pragma unroll
        for (int d = 1; d < 64; d <<= 1) s += __shfl_xor(s, d, 64);
        float a = e / s;
        attnS[wid * 64 + lane] = a;
        attnO[(size_t)(atom0 + wid) * MD + lane] = a;
    }
    __syncthreads();

    float aggp[8] = {0.f, 0.f, 0.f, 0.f, 0.f, 0.f, 0.f, 0.f};
#pragma unroll
    for (int mt = 0; mt < 2; ++mt)
#pragma unroll
        for (int r = 0; r < 4; ++r) {
            float a = attnS[rw + mt * 16 + quad * 4 + r];
#pragma unroll
            for (int nt = 0; nt < 8; ++nt) aggp[nt] += a * acc2[mt][nt][r];
        }
#pragma unroll
    for (int d = 16; d < 64; d <<= 1)
#pragma unroll
        for (int nt = 0; nt < 8; ++nt) aggp[nt] += __shfl_xor(aggp[nt], d, 64);
    if (quad == 0) {
#pragma unroll
        for (int nt = 0; nt < 8; ++nt) aggS[wid * 128 + nt * 16 + col] = aggp[nt];
    }
    __syncthreads();
    {
        int a = tid >> 7;   // which atom
        int c = tid & 127;  // feature
        float v = aggS[(2 * a) * 128 + c] + aggS[(2 * a + 1) * 128 + c];
        aggOut[(size_t)(atom0 + a) * FD + c] = v;  // agg scratch in d_out rows
    }
}

// ---------------- k3: out = tanh(agg@Wo1+bo1)@Wo2+bo2, IN PLACE on d_out rows ----------------
__global__ __launch_bounds__(256, 3) void k3_out(
    float* __restrict__ outp, const u16* __restrict__ Wo1T,
    const u16* __restrict__ Wo2T, const float* __restrict__ bo1,
    const float* __restrict__ bo2) {
    __shared__ alignas(16) char smem[53248];
    u16* sA = (u16*)smem;            // [128][136]: agg rows, then t1
    u16* sW = (u16*)(smem + 34816);  // [128][72] panel
    const int tid = threadIdx.x, wid = tid >> 6, lane = tid & 63;
    const int quad = lane >> 4, col = lane & 15, rw = wid * 32;
    const int row0 = blockIdx.x * 128;

    // stage agg (fp32, from d_out) -> bf16 LDS; ALL reads before first barrier
    for (int i = tid; i < 4096; i += 256) {
        int r = i >> 5, c = (i & 31) * 4;
        int gr = row0 + r;
        float4 v = {0.f, 0.f, 0.f, 0.f};
        if (gr < TOTAL) v = *(const float4*)&outp[(size_t)gr * FD + c];
        u32* p = (u32*)&sA[r * 136 + c];
        p[0] = pkbf(v.x, v.y);
        p[1] = pkbf(v.z, v.w);
    }
    for (int i = tid; i < 1152; i += 256) ((int4*)sW)[i] = ((const int4*)Wo1T)[i];
    __syncthreads();

    f32x4 acc[2][8];
    const f32x4 zf = {0.f, 0.f, 0.f, 0.f};
#pragma unroll
    for (int mt = 0; mt < 2; ++mt)
#pragma unroll
        for (int nt = 0; nt < 8; ++nt) acc[mt][nt] = zf;
    for (int half = 0; half < 2; ++half) {
        if (half) {
            __syncthreads();
            for (int i = tid; i < 1152; i += 256)
                ((int4*)sW)[i] = ((const int4*)(Wo1T + 9216))[i];
            __syncthreads();
        }
#pragma unroll
        for (int ks = 0; ks < 2; ++ks) {
            const int ka = half * 64 + ks * 32 + quad * 8;
            const int kb = ks * 32 + quad * 8;
            short8 a0 = *(const short8*)&sA[(rw + col) * 136 + ka];
            short8 a1 = *(const short8*)&sA[(rw + 16 + col) * 136 + ka];
#pragma unroll
            for (int nt = 0; nt < 8; ++nt) {
                short8 bfr = *(const short8*)&sW[(nt * 16 + col) * 72 + kb];
                acc[0][nt] = mfma16(a0, bfr, acc[0][nt]);
                acc[1][nt] = mfma16(a1, bfr, acc[1][nt]);
            }
        }
    }
    __syncthreads();  // layer-1 A reads done before t1 overwrite

    float bias[8];
#pragma unroll
    for (int nt = 0; nt < 8; ++nt) bias[nt] = bo1[nt * 16 + col];
#pragma unroll
    for (int mt = 0; mt < 2; ++mt)
#pragma unroll
        for (int nt = 0; nt < 8; ++nt)
#pragma unroll
            for (int r = 0; r < 4; ++r) {
                int row = rw + mt * 16 + quad * 4 + r;
                sA[row * 136 + nt * 16 + col] =
                    f2bf(tanh_fast(acc[mt][nt][r] + bias[nt]));
            }
    for (int i = tid; i < 1152; i += 256) ((int4*)sW)[i] = ((const int4*)Wo2T)[i];
    __syncthreads();

    f32x4 acc2[2][8];
#pragma unroll
    for (int mt = 0; mt < 2; ++mt)
#pragma unroll
        for (int nt = 0; nt < 8; ++nt) acc2[mt][nt] = zf;
    for (int half = 0; half < 2; ++half) {
        if (half) {
            __syncthreads();
            for (int i = tid; i < 1152; i += 256)
                ((int4*)sW)[i] = ((const int4*)(Wo2T + 9216))[i];
            __syncthreads();
        }
#pragma unroll
        for (int ks = 0; ks < 2; ++ks) {
            const int ka = half * 64 + ks * 32 + quad * 8;
            const int kb = ks * 32 + quad * 8;
            short8 a0 = *(const short8*)&sA[(rw + col) * 136 + ka];
            short8 a1 = *(const short8*)&sA[(rw + 16 + col) * 136 + ka];
#pragma unroll
            for (int nt = 0; nt < 8; ++nt) {
                short8 bfr = *(const short8*)&sW[(nt * 16 + col) * 72 + kb];
                acc2[0][nt] = mfma16(a0, bfr, acc2[0][nt]);
                acc2[1][nt] = mfma16(a1, bfr, acc2[1][nt]);
            }
        }
    }
#pragma unroll
    for (int nt = 0; nt < 8; ++nt) bias[nt] = bo2[nt * 16 + col];
#pragma unroll
    for (int mt = 0; mt < 2; ++mt)
#pragma unroll
        for (int nt = 0; nt < 8; ++nt)
#pragma unroll
            for (int r = 0; r < 4; ++r) {
                int row = rw + mt * 16 + quad * 4 + r;
                int gr = row0 + row;
                if (gr < TOTAL)
                    outp[(size_t)gr * FD + nt * 16 + col] =
                        acc2[mt][nt][r] + bias[nt];
            }
}

extern "C" void kernel_launch(void* const* d_in, const int* in_sizes, int n_in,
                              void* d_out, int out_size, void* d_ws,
                              size_t ws_size, hipStream_t stream) {
    const float* feat = (const float*)d_in[0];
    const float* rbf  = (const float*)d_in[1];
    const int*   nl   = (const int*)d_in[2];
    const float* Wi   = (const float*)d_in[3];
    const float* W1   = (const float*)d_in[4];
    const float* b1   = (const float*)d_in[5];
    const float* W2   = (const float*)d_in[6];
    const float* b2   = (const float*)d_in[7];
    const float* nbrw = (const float*)d_in[8];
    const float* Wo1  = (const float*)d_in[9];
    const float* bo1  = (const float*)d_in[10];
    const float* Wo2  = (const float*)d_in[11];
    const float* bo2  = (const float*)d_in[12];

    float* outp  = (float*)d_out;               // [8000][128] (agg scratch, then final)
    float* attnp = outp + (size_t)TOTAL * FD;   // [8000][64]

    char* ws = (char*)d_ws;                     // total use: 2,213,888 B
    u16* initB = (u16*)ws;                      // 2,048,000 B
    u16* W1T   = (u16*)(ws + 2048000);          // 18,432 B
    u16* W2T   = (u16*)(ws + 2048000 + 18432);  // 36,864 B
    u16* WiT   = (u16*)(ws + 2048000 + 18432 + 36864);
    u16* Wo1T  = (u16*)(ws + 2048000 + 18432 + 2 * 36864);
    u16* Wo2T  = (u16*)(ws + 2048000 + 18432 + 3 * 36864);

    hipLaunchKernelGGL(k0_prep, dim3(40), dim3(256), 0, stream,
                       W1, W2, Wi, Wo1, Wo2, W1T, W2T, WiT, Wo1T, Wo2T);
    hipLaunchKernelGGL(k1_init, dim3(63), dim3(256), 0, stream, feat, WiT, initB);
    hipLaunchKernelGGL(k2_main, dim3(4000), dim3(256), 0, stream,
                       rbf, nl, initB, W1T, W2T, b1, b2, nbrw, outp, attnp);
    hipLaunchKernelGGL(k3_out, dim3(63), dim3(256), 0, stream,
                       outp, Wo1T, Wo2T, bo1, bo2);
}